// Round 1
// baseline (484.848 us; speedup 1.0000x reference)
//
#include <hip/hip_runtime.h>

#define TPB 256
#define BATCH 2
#define S_TOT 16384        // 16*32*32 spatial positions
#define DZ 16
#define HY 32
#define WX 32
#define NST 16
#define NCHUNK 256
#define CLEN 64            // NCHUNK*CLEN == S_TOT
#define EPS 1e-5f
#define SLOPE 0.01f

__device__ __forceinline__ float leakyf(float v){ return v > 0.f ? v : SLOPE * v; }

// ---------------- upsample (ConvTranspose3d k=2 s=2) + concat ----------------
// xcat[n, ch, s]: ch<32 -> x2 copy; ch>=32 -> upsampled x1
__global__ __launch_bounds__(TPB) void k_upconcat(
    const float* __restrict__ x1, const float* __restrict__ x2,
    const float* __restrict__ upw, const float* __restrict__ upb,
    float* __restrict__ xcat) {
  int idx = blockIdx.x * TPB + threadIdx.x;        // 2*64*16384
  int s  = idx & 16383;
  int ch = (idx >> 14) & 63;
  int n  = idx >> 20;
  if (ch < 32) { xcat[idx] = x2[(n*32 + ch)*S_TOT + s]; return; }
  int o = ch - 32;
  int z = s >> 10, y = (s >> 5) & 31, x = s & 31;
  int zi = z >> 1, yi = y >> 1, xi = x >> 1;
  int tap = ((z & 1) * 2 + (y & 1)) * 2 + (x & 1); // i*4+j*2+k
  float acc = upb[o];
  int xbase = (n*32)*2048 + zi*256 + yi*16 + xi;   // x1 c-stride 2048
  int wbase = o*8 + tap;                           // upw c-stride 256
  #pragma unroll 8
  for (int c = 0; c < 32; c++)
    acc += x1[xbase + c*2048] * upw[wbase + c*256];
  xcat[idx] = acc;
}

// ---------------- dc1: 1x1x1 conv 64->32, raw out + stats ----------------
__global__ __launch_bounds__(TPB) void k_conv1(
    const float* __restrict__ xcat, const float* __restrict__ w,
    const float* __restrict__ bias, float* __restrict__ c1,
    float* __restrict__ st1) {
  __shared__ float ws[64];
  __shared__ float red[2][4];
  int bid = blockIdx.x, t = threadIdx.x;
  int s = ((bid & 63) << 8) + t, c = (bid >> 6) & 31, n = bid >> 11;
  if (t < 64) ws[t] = w[c*64 + t];
  __syncthreads();
  const float* xin = xcat + n*64*S_TOT + s;
  float acc = bias[c];
  #pragma unroll 8
  for (int i = 0; i < 64; i++) acc += xin[i*S_TOT] * ws[i];
  c1[(n*32 + c)*S_TOT + s] = acc;
  float sm = acc, sq = acc*acc;
  #pragma unroll
  for (int o = 32; o > 0; o >>= 1) { sm += __shfl_down(sm, o); sq += __shfl_down(sq, o); }
  int lane = t & 63, wv = t >> 6;
  if (lane == 0) { red[0][wv] = sm; red[1][wv] = sq; }
  __syncthreads();
  if (t == 0) {
    float a = red[0][0]+red[0][1]+red[0][2]+red[0][3];
    float b = red[1][0]+red[1][1]+red[1][2]+red[1][3];
    atomicAdd(&st1[(n*32+c)*2], a); atomicAdd(&st1[(n*32+c)*2+1], b);
  }
}

// ---------------- dc2: 3x3x3 grouped conv (8 groups), IN(c1)+leaky applied on read ----------------
__global__ __launch_bounds__(TPB) void k_conv2(
    const float* __restrict__ c1, const float* __restrict__ w,
    const float* __restrict__ bias, const float* __restrict__ st1,
    float* __restrict__ c2, float* __restrict__ st2) {
  __shared__ float ws[108];
  __shared__ float mrs[4][2];
  __shared__ float red[2][4];
  int bid = blockIdx.x, t = threadIdx.x;
  int s = ((bid & 63) << 8) + t, c = (bid >> 6) & 31, n = bid >> 11;
  if (t < 108) ws[t] = w[c*108 + t];
  if (t < 4) {
    int ci = (c >> 2)*4 + t;
    float s0 = st1[(n*32+ci)*2], s1 = st1[(n*32+ci)*2+1];
    float m = s0 * (1.f/S_TOT);
    mrs[t][0] = m; mrs[t][1] = rsqrtf(s1*(1.f/S_TOT) - m*m + EPS);
  }
  __syncthreads();
  int z = s >> 10, y = (s >> 5) & 31, x = s & 31;
  const float* base = c1 + (n*32 + (c >> 2)*4)*S_TOT;
  float acc = bias[c];
  for (int i = 0; i < 4; i++) {
    float m = mrs[i][0], rs = mrs[i][1];
    const float* pin = base + i*S_TOT;
    #pragma unroll
    for (int dz = -1; dz <= 1; dz++) {
      int zz = z + dz; if (zz < 0 || zz >= DZ) continue;
      #pragma unroll
      for (int dy = -1; dy <= 1; dy++) {
        int yy = y + dy; if (yy < 0 || yy >= HY) continue;
        #pragma unroll
        for (int dx = -1; dx <= 1; dx++) {
          int xx = x + dx; if (xx < 0 || xx >= WX) continue;
          float v = pin[zz*1024 + yy*32 + xx];
          v = leakyf((v - m) * rs);
          acc += v * ws[i*27 + (dz+1)*9 + (dy+1)*3 + (dx+1)];
        }
      }
    }
  }
  c2[(n*32 + c)*S_TOT + s] = acc;
  float sm = acc, sq = acc*acc;
  #pragma unroll
  for (int o = 32; o > 0; o >>= 1) { sm += __shfl_down(sm, o); sq += __shfl_down(sq, o); }
  int lane = t & 63, wv = t >> 6;
  if (lane == 0) { red[0][wv] = sm; red[1][wv] = sq; }
  __syncthreads();
  if (t == 0) {
    float a = red[0][0]+red[0][1]+red[0][2]+red[0][3];
    float b = red[1][0]+red[1][1]+red[1][2]+red[1][3];
    atomicAdd(&st2[(n*32+c)*2], a); atomicAdd(&st2[(n*32+c)*2+1], b);
  }
}

// ---------------- dc3: 1x1x1 conv 32->32, IN(c2)+leaky on read ----------------
__global__ __launch_bounds__(TPB) void k_conv3(
    const float* __restrict__ c2, const float* __restrict__ w,
    const float* __restrict__ bias, const float* __restrict__ st2,
    float* __restrict__ c3, float* __restrict__ st3) {
  __shared__ float ws[32];
  __shared__ float mrs[32][2];
  __shared__ float red[2][4];
  int bid = blockIdx.x, t = threadIdx.x;
  int s = ((bid & 63) << 8) + t, c = (bid >> 6) & 31, n = bid >> 11;
  if (t < 32) {
    ws[t] = w[c*32 + t];
    float s0 = st2[(n*32+t)*2], s1 = st2[(n*32+t)*2+1];
    float m = s0 * (1.f/S_TOT);
    mrs[t][0] = m; mrs[t][1] = rsqrtf(s1*(1.f/S_TOT) - m*m + EPS);
  }
  __syncthreads();
  const float* pin = c2 + n*32*S_TOT + s;
  float acc = bias[c];
  #pragma unroll 8
  for (int i = 0; i < 32; i++) {
    float v = pin[i*S_TOT];
    v = leakyf((v - mrs[i][0]) * mrs[i][1]);
    acc += v * ws[i];
  }
  c3[(n*32 + c)*S_TOT + s] = acc;
  float sm = acc, sq = acc*acc;
  #pragma unroll
  for (int o = 32; o > 0; o >>= 1) { sm += __shfl_down(sm, o); sq += __shfl_down(sq, o); }
  int lane = t & 63, wv = t >> 6;
  if (lane == 0) { red[0][wv] = sm; red[1][wv] = sq; }
  __syncthreads();
  if (t == 0) {
    float a = red[0][0]+red[0][1]+red[0][2]+red[0][3];
    float b = red[1][0]+red[1][1]+red[1][2]+red[1][3];
    atomicAdd(&st3[(n*32+c)*2], a); atomicAdd(&st3[(n*32+c)*2+1], b);
  }
}

// ---------------- IN(c3)+leaky + LayerNorm -> token-major tln[token*32+c] ----------------
__global__ __launch_bounds__(TPB) void k_ln(
    const float* __restrict__ c3, const float* __restrict__ st3,
    const float* __restrict__ lnw, const float* __restrict__ lnb,
    float* __restrict__ tln) {
  __shared__ float mrs[32][2];
  __shared__ float wsh[32], bsh[32];
  int bid = blockIdx.x, t = threadIdx.x;
  int n = bid >> 6; int s = ((bid & 63) << 8) + t;
  if (t < 32) {
    float s0 = st3[(n*32+t)*2], s1 = st3[(n*32+t)*2+1];
    float m = s0 * (1.f/S_TOT);
    mrs[t][0] = m; mrs[t][1] = rsqrtf(s1*(1.f/S_TOT) - m*m + EPS);
    wsh[t] = lnw[t]; bsh[t] = lnb[t];
  }
  __syncthreads();
  float xv[32]; float mean = 0.f;
  #pragma unroll
  for (int c = 0; c < 32; c++) {
    float v = c3[(n*32 + c)*S_TOT + s];
    v = leakyf((v - mrs[c][0]) * mrs[c][1]);
    xv[c] = v; mean += v;
  }
  mean *= (1.f/32.f);
  float var = 0.f;
  #pragma unroll
  for (int c = 0; c < 32; c++) { float d = xv[c] - mean; var += d*d; }
  float rstd = rsqrtf(var*(1.f/32.f) + EPS);
  int token = n*S_TOT + s;
  #pragma unroll
  for (int c = 0; c < 32; c++)
    tln[token*32 + c] = (xv[c] - mean)*rstd*wsh[c] + bsh[c];
}

// ---------------- in_proj: [32k,32]@[32,128]^T -> xi[.,64], z[.,64] ----------------
#define IPT 16
__global__ __launch_bounds__(TPB) void k_inproj(
    const float* __restrict__ tln, const float* __restrict__ ipw,
    float* __restrict__ xi, float* __restrict__ zb) {
  __shared__ float wT[4096];      // transposed: wT[c*128+f]
  __shared__ float tk[IPT][32];
  int t = threadIdx.x; int token0 = blockIdx.x * IPT;
  for (int i = t; i < 4096; i += TPB) { int f = i >> 5, c = i & 31; wT[c*128 + f] = ipw[i]; }
  for (int i = t; i < IPT*32; i += TPB) { int lt = i >> 5, c = i & 31; tk[lt][c] = tln[(token0+lt)*32 + c]; }
  __syncthreads();
  int f = t & 127;
  for (int lt = t >> 7; lt < IPT; lt += 2) {
    float acc = 0.f;
    #pragma unroll
    for (int c = 0; c < 32; c++) acc += wT[c*128 + f] * tk[lt][c];
    int token = token0 + lt;
    if (f < 64) xi[token*64 + f] = acc;
    else        zb[token*64 + (f - 64)] = acc;
  }
}

// ---------------- causal depthwise conv1d + SiLU, then x_proj + dt_proj/softplus ----------------
__global__ __launch_bounds__(TPB) void k_conv1d(
    const float* __restrict__ xi, const float* __restrict__ c1w,
    const float* __restrict__ c1b, const float* __restrict__ xpw,
    const float* __restrict__ dtw, const float* __restrict__ dtbi,
    float* __restrict__ u, float* __restrict__ dt,
    float* __restrict__ Bb, float* __restrict__ Cc) {
  __shared__ float xpT[2176];     // transposed: xpT[dd*34+f]
  __shared__ float uu[4][64];
  __shared__ float xd[4][34];
  int t = threadIdx.x;
  for (int i = t; i < 2176; i += TPB) { int f = i >> 6, dd = i & 63; xpT[dd*34 + f] = xpw[i]; }
  __syncthreads();
  int lt = t >> 6, ch = t & 63;
  for (int it = 0; it < 4; it++) {
    int token = blockIdx.x*16 + it*4 + lt;
    int n = token >> 14, s = token & 16383;
    float acc = c1b[ch];
    #pragma unroll
    for (int j = 0; j < 4; j++) {
      int sp = s - 3 + j;
      float v = (sp >= 0) ? xi[((n << 14) + sp)*64 + ch] : 0.f;
      acc += v * c1w[ch*4 + j];
    }
    float uv = acc / (1.f + __expf(-acc));          // silu
    u[token*64 + ch] = uv;
    uu[lt][ch] = uv;
    __syncthreads();
    if (ch < 34) {
      float a = 0.f;
      #pragma unroll
      for (int dd = 0; dd < 64; dd++) a += xpT[dd*34 + ch] * uu[lt][dd];
      xd[lt][ch] = a;
    }
    __syncthreads();
    float dv = xd[lt][0]*dtw[ch*2] + xd[lt][1]*dtw[ch*2+1] + dtbi[ch];
    dt[token*64 + ch] = fmaxf(dv, 0.f) + log1pf(__expf(-fabsf(dv)));  // softplus
    if (ch < 16)       Bb[token*16 + ch]        = xd[lt][2 + ch];
    else if (ch < 32)  Cc[token*16 + (ch - 16)] = xd[lt][2 + ch];
    __syncthreads();
  }
}

// ---------------- scan phase 1: per-chunk local scan + aggregates ----------------
__global__ __launch_bounds__(TPB) void k_scan1(
    const float* __restrict__ dt, const float* __restrict__ u,
    const float* __restrict__ Bb, const float* __restrict__ Alog,
    float* __restrict__ cA, float* __restrict__ cX) {
  int tid = blockIdx.x*TPB + threadIdx.x;   // 32768
  int d = tid & 63, b = (tid >> 6) & 1, chunk = tid >> 7;
  float Ar[16];
  #pragma unroll
  for (int nn = 0; nn < 16; nn++) Ar[nn] = -__expf(Alog[d*16 + nn]);
  float h[16];
  #pragma unroll
  for (int nn = 0; nn < 16; nn++) h[nn] = 0.f;
  float sdt = 0.f;
  int tg0 = b*S_TOT + chunk*CLEN;
  for (int tt = 0; tt < CLEN; tt++) {
    int tg = tg0 + tt;
    float dtv = dt[tg*64 + d], uv = u[tg*64 + d];
    sdt += dtv;
    float du = dtv * uv;
    const float4* bp = (const float4*)(Bb + tg*16);
    float4 q0 = bp[0], q1 = bp[1], q2 = bp[2], q3 = bp[3];
    float Bv[16] = {q0.x,q0.y,q0.z,q0.w, q1.x,q1.y,q1.z,q1.w,
                    q2.x,q2.y,q2.z,q2.w, q3.x,q3.y,q3.z,q3.w};
    #pragma unroll
    for (int nn = 0; nn < 16; nn++)
      h[nn] = __expf(Ar[nn]*dtv)*h[nn] + Bv[nn]*du;
  }
  int cbase = ((b*64 + d)*NCHUNK + chunk)*16;
  #pragma unroll
  for (int nn = 0; nn < 16; nn++) {
    cA[cbase + nn] = __expf(Ar[nn]*sdt);
    cX[cbase + nn] = h[nn];
  }
}

// ---------------- scan phase 2: exclusive prefix over chunk aggregates ----------------
__global__ __launch_bounds__(TPB) void k_scan2(
    const float* __restrict__ cA, float* __restrict__ cX) {
  int tid = blockIdx.x*TPB + threadIdx.x;   // 2048
  int nn = tid & 15, rest = tid >> 4;       // rest = b*64+d
  int base = rest*NCHUNK*16 + nn;
  float h = 0.f;
  for (int c = 0; c < NCHUNK; c++) {
    int i = base + c*16;
    float a = cA[i], x = cX[i];
    cX[i] = h;
    h = a*h + x;
  }
}

// ---------------- scan phase 3: seeded replay + y = h.C + u*D, gate silu(z) ----------------
__global__ __launch_bounds__(TPB) void k_scan3(
    const float* __restrict__ dt, const float* __restrict__ u,
    const float* __restrict__ Bb, const float* __restrict__ Cc,
    const float* __restrict__ Alog, const float* __restrict__ Dp,
    const float* __restrict__ zb, const float* __restrict__ cX,
    float* __restrict__ g) {
  int tid = blockIdx.x*TPB + threadIdx.x;
  int d = tid & 63, b = (tid >> 6) & 1, chunk = tid >> 7;
  float Ar[16];
  #pragma unroll
  for (int nn = 0; nn < 16; nn++) Ar[nn] = -__expf(Alog[d*16 + nn]);
  float h[16];
  int cbase = ((b*64 + d)*NCHUNK + chunk)*16;
  #pragma unroll
  for (int nn = 0; nn < 16; nn++) h[nn] = cX[cbase + nn];
  float Dv = Dp[d];
  int tg0 = b*S_TOT + chunk*CLEN;
  for (int tt = 0; tt < CLEN; tt++) {
    int tg = tg0 + tt;
    float dtv = dt[tg*64 + d], uv = u[tg*64 + d];
    float du = dtv * uv;
    const float4* bp = (const float4*)(Bb + tg*16);
    const float4* cp = (const float4*)(Cc + tg*16);
    float4 q0 = bp[0], q1 = bp[1], q2 = bp[2], q3 = bp[3];
    float4 r0 = cp[0], r1 = cp[1], r2 = cp[2], r3 = cp[3];
    float Bv[16] = {q0.x,q0.y,q0.z,q0.w, q1.x,q1.y,q1.z,q1.w,
                    q2.x,q2.y,q2.z,q2.w, q3.x,q3.y,q3.z,q3.w};
    float Cv[16] = {r0.x,r0.y,r0.z,r0.w, r1.x,r1.y,r1.z,r1.w,
                    r2.x,r2.y,r2.z,r2.w, r3.x,r3.y,r3.z,r3.w};
    float y = uv * Dv;
    #pragma unroll
    for (int nn = 0; nn < 16; nn++) {
      h[nn] = __expf(Ar[nn]*dtv)*h[nn] + Bv[nn]*du;
      y += h[nn]*Cv[nn];
    }
    float zv = zb[tg*64 + d];
    g[tg*64 + d] = y * (zv / (1.f + __expf(-zv)));
  }
}

// ---------------- out_proj: out[b,c,s] = sum_d g[b,s,d]*opw[c,d] ----------------
__global__ __launch_bounds__(TPB) void k_out(
    const float* __restrict__ g, const float* __restrict__ opw,
    float* __restrict__ out) {
  __shared__ float wrow[64];
  int bid = blockIdx.x, t = threadIdx.x;
  int s = ((bid & 63) << 8) + t, c = (bid >> 6) & 31, n = bid >> 11;
  if (t < 64) wrow[t] = opw[c*64 + t];
  __syncthreads();
  const float4* gp = (const float4*)(g + ((n << 14) + s)*64);
  float acc = 0.f;
  #pragma unroll
  for (int q = 0; q < 16; q++) {
    float4 v = gp[q];
    acc += v.x*wrow[4*q] + v.y*wrow[4*q+1] + v.z*wrow[4*q+2] + v.w*wrow[4*q+3];
  }
  out[(n*32 + c)*S_TOT + s] = acc;
}

extern "C" void kernel_launch(void* const* d_in, const int* in_sizes, int n_in,
                              void* d_out, int out_size, void* d_ws, size_t ws_size,
                              hipStream_t stream) {
  const float* x1    = (const float*)d_in[0];
  const float* x2    = (const float*)d_in[1];
  const float* upw   = (const float*)d_in[2];
  const float* upb   = (const float*)d_in[3];
  const float* dc1w  = (const float*)d_in[4];
  const float* dc1b  = (const float*)d_in[5];
  const float* dc2w  = (const float*)d_in[6];
  const float* dc2b  = (const float*)d_in[7];
  const float* dc3w  = (const float*)d_in[8];
  const float* dc3b  = (const float*)d_in[9];
  const float* lnw   = (const float*)d_in[10];
  const float* lnb   = (const float*)d_in[11];
  const float* ipw   = (const float*)d_in[12];
  const float* c1w   = (const float*)d_in[13];
  const float* c1b   = (const float*)d_in[14];
  const float* xpw   = (const float*)d_in[15];
  const float* dtw   = (const float*)d_in[16];
  const float* dtbi  = (const float*)d_in[17];
  const float* Alog  = (const float*)d_in[18];
  const float* Dp    = (const float*)d_in[19];
  const float* opw   = (const float*)d_in[20];
  float* out = (float*)d_out;

  float* ws   = (float*)d_ws;
  float* xcat = ws + 0;            // 2,097,152  (reused: c3 -> xi -> g)
  float* c1   = ws + 2097152;      // 1,048,576  (reused: tln -> Bb|Cc)
  float* c2   = ws + 3145728;      // 1,048,576
  float* zb   = ws + 4194304;      // 2,097,152
  float* ub   = ws + 6291456;      // 2,097,152
  float* dtb  = ws + 8388608;      // 2,097,152
  float* cA   = ws + 10485760;     // 524,288
  float* cX   = ws + 11010048;     // 524,288
  float* st   = ws + 11534336;     // 384 = st1|st2|st3
  float* st1 = st, *st2 = st + 128, *st3 = st + 256;
  float* c3   = xcat;
  float* tln  = c1;
  float* xi   = xcat;
  float* Bb   = c1;
  float* Cc   = c1 + BATCH*S_TOT*NST;
  float* gbuf = xcat;

  hipMemsetAsync(st, 0, 384*sizeof(float), stream);
  k_upconcat<<<8192, TPB, 0, stream>>>(x1, x2, upw, upb, xcat);
  k_conv1  <<<4096, TPB, 0, stream>>>(xcat, dc1w, dc1b, c1, st1);
  k_conv2  <<<4096, TPB, 0, stream>>>(c1, dc2w, dc2b, st1, c2, st2);
  k_conv3  <<<4096, TPB, 0, stream>>>(c2, dc3w, dc3b, st2, c3, st3);
  k_ln     <<<128,  TPB, 0, stream>>>(c3, st3, lnw, lnb, tln);
  k_inproj <<<2048, TPB, 0, stream>>>(tln, ipw, xi, zb);
  k_conv1d <<<2048, TPB, 0, stream>>>(xi, c1w, c1b, xpw, dtw, dtbi, ub, dtb, Bb, Cc);
  k_scan1  <<<128,  TPB, 0, stream>>>(dtb, ub, Bb, Alog, cA, cX);
  k_scan2  <<<8,    TPB, 0, stream>>>(cA, cX);
  k_scan3  <<<128,  TPB, 0, stream>>>(dtb, ub, Bb, Cc, Alog, Dp, zb, cX, gbuf);
  k_out    <<<4096, TPB, 0, stream>>>(gbuf, opw, out);
}

// Round 3
// 383.005 us; speedup vs baseline: 1.2659x; 1.2659x over previous
//
#include <hip/hip_runtime.h>

#define TPB 256
#define BATCH 2
#define S_TOT 16384        // 16*32*32 spatial positions
#define DZ 16
#define HY 32
#define WX 32
#define NST 16
#define NCHUNK 256
#define CLEN 64            // NCHUNK*CLEN == S_TOT
#define EPS 1e-5f
#define SLOPE 0.01f

__device__ __forceinline__ float leakyf(float v){ return v > 0.f ? v : SLOPE * v; }

// ---------------- upsample (ConvTranspose3d k=2 s=2) + concat ----------------
__global__ __launch_bounds__(TPB) void k_upconcat(
    const float* __restrict__ x1, const float* __restrict__ x2,
    const float* __restrict__ upw, const float* __restrict__ upb,
    float* __restrict__ xcat) {
  int idx = blockIdx.x * TPB + threadIdx.x;        // 2*64*16384
  int s  = idx & 16383;
  int ch = (idx >> 14) & 63;
  int n  = idx >> 20;
  if (ch < 32) { xcat[idx] = x2[(n*32 + ch)*S_TOT + s]; return; }
  int o = ch - 32;
  int z = s >> 10, y = (s >> 5) & 31, x = s & 31;
  int zi = z >> 1, yi = y >> 1, xi = x >> 1;
  int tap = ((z & 1) * 2 + (y & 1)) * 2 + (x & 1);
  float acc = upb[o];
  int xbase = (n*32)*2048 + zi*256 + yi*16 + xi;
  int wbase = o*8 + tap;
  #pragma unroll 8
  for (int c = 0; c < 32; c++)
    acc += x1[xbase + c*2048] * upw[wbase + c*256];
  xcat[idx] = acc;
}

// ---------------- dc1: 1x1x1 conv 64->32, raw out + stats ----------------
__global__ __launch_bounds__(TPB) void k_conv1(
    const float* __restrict__ xcat, const float* __restrict__ w,
    const float* __restrict__ bias, float* __restrict__ c1,
    float* __restrict__ st1) {
  __shared__ float ws[64];
  __shared__ float red[2][4];
  int bid = blockIdx.x, t = threadIdx.x;
  int s = ((bid & 63) << 8) + t, c = (bid >> 6) & 31, n = bid >> 11;
  if (t < 64) ws[t] = w[c*64 + t];
  __syncthreads();
  const float* xin = xcat + n*64*S_TOT + s;
  float acc = bias[c];
  #pragma unroll 8
  for (int i = 0; i < 64; i++) acc += xin[i*S_TOT] * ws[i];
  c1[(n*32 + c)*S_TOT + s] = acc;
  float sm = acc, sq = acc*acc;
  #pragma unroll
  for (int o = 32; o > 0; o >>= 1) { sm += __shfl_down(sm, o); sq += __shfl_down(sq, o); }
  int lane = t & 63, wv = t >> 6;
  if (lane == 0) { red[0][wv] = sm; red[1][wv] = sq; }
  __syncthreads();
  if (t == 0) {
    float a = red[0][0]+red[0][1]+red[0][2]+red[0][3];
    float b = red[1][0]+red[1][1]+red[1][2]+red[1][3];
    atomicAdd(&st1[(n*32+c)*2], a); atomicAdd(&st1[(n*32+c)*2+1], b);
  }
}

// ---------------- IN(c1)+leaky into zero-padded buffer pn[n][c][18][34][34] ----------------
__global__ __launch_bounds__(TPB) void k_pad_norm(
    const float* __restrict__ c1, const float* __restrict__ st1,
    float* __restrict__ pn) {
  int idx = blockIdx.x * TPB + threadIdx.x;   // 2*32*16384
  int s = idx & 16383;
  int c = (idx >> 14) & 31;
  int n = idx >> 19;
  float s0 = st1[(n*32+c)*2], s1 = st1[(n*32+c)*2+1];
  float m = s0 * (1.f/S_TOT);
  float rs = rsqrtf(s1*(1.f/S_TOT) - m*m + EPS);
  float v = leakyf((c1[(n*32+c)*S_TOT + s] - m) * rs);
  int z = s >> 10, y = (s >> 5) & 31, x = s & 31;
  pn[((n*32+c)*18 + z+1)*1156 + (y+1)*34 + (x+1)] = v;
}

// ---------------- dc2: 3x3x3 grouped conv, 4 outputs/thread, padded input ----------------
__global__ __launch_bounds__(TPB) void k_conv2(
    const float* __restrict__ pn, const float* __restrict__ w,
    const float* __restrict__ bias, float* __restrict__ c2,
    float* __restrict__ st2) {
  __shared__ float ws[432];       // [oc][108]
  __shared__ float red[4][4][2];  // [wave][oc][m]
  int bid = blockIdx.x, t = threadIdx.x;
  int s = ((bid & 63) << 8) + t;
  int g = (bid >> 6) & 7;
  int n = bid >> 9;
  for (int i = t; i < 432; i += TPB) ws[i] = w[(g*4)*108 + i];
  __syncthreads();
  int z = s >> 10, y = (s >> 5) & 31, x = s & 31;
  float acc[4];
  #pragma unroll
  for (int oc = 0; oc < 4; oc++) acc[oc] = bias[g*4 + oc];
  const float* pbase = pn + ((n*32 + g*4)*18)*1156;
  #pragma unroll
  for (int ic = 0; ic < 4; ic++) {
    const float* pc = pbase + ic*(18*1156);
    #pragma unroll
    for (int dz = 0; dz < 3; dz++) {
      #pragma unroll
      for (int dy = 0; dy < 3; dy++) {
        const float* pr = pc + (z+dz)*1156 + (y+dy)*34 + x;
        float p0 = pr[0], p1 = pr[1], p2 = pr[2];
        int wb = ic*27 + dz*9 + dy*3;
        #pragma unroll
        for (int oc = 0; oc < 4; oc++) {
          const float* wo = &ws[oc*108 + wb];
          acc[oc] += p0*wo[0] + p1*wo[1] + p2*wo[2];
        }
      }
    }
  }
  float sm[4], sq[4];
  #pragma unroll
  for (int oc = 0; oc < 4; oc++) {
    c2[(n*32 + g*4 + oc)*S_TOT + s] = acc[oc];
    sm[oc] = acc[oc]; sq[oc] = acc[oc]*acc[oc];
  }
  #pragma unroll
  for (int o = 32; o > 0; o >>= 1) {
    #pragma unroll
    for (int oc = 0; oc < 4; oc++) {
      sm[oc] += __shfl_down(sm[oc], o);
      sq[oc] += __shfl_down(sq[oc], o);
    }
  }
  int lane = t & 63, wv = t >> 6;
  if (lane == 0) {
    #pragma unroll
    for (int oc = 0; oc < 4; oc++) { red[wv][oc][0] = sm[oc]; red[wv][oc][1] = sq[oc]; }
  }
  __syncthreads();
  if (t < 8) {
    int oc = t & 3, m = t >> 2;
    float a = red[0][oc][m] + red[1][oc][m] + red[2][oc][m] + red[3][oc][m];
    atomicAdd(&st2[(n*32 + g*4 + oc)*2 + m], a);
  }
}

// ---------------- dc3: 1x1x1 conv 32->32, IN(c2)+leaky on read ----------------
__global__ __launch_bounds__(TPB) void k_conv3(
    const float* __restrict__ c2, const float* __restrict__ w,
    const float* __restrict__ bias, const float* __restrict__ st2,
    float* __restrict__ c3, float* __restrict__ st3) {
  __shared__ float ws[32];
  __shared__ float mrs[32][2];
  __shared__ float red[2][4];
  int bid = blockIdx.x, t = threadIdx.x;
  int s = ((bid & 63) << 8) + t, c = (bid >> 6) & 31, n = bid >> 11;
  if (t < 32) {
    ws[t] = w[c*32 + t];
    float s0 = st2[(n*32+t)*2], s1 = st2[(n*32+t)*2+1];
    float m = s0 * (1.f/S_TOT);
    mrs[t][0] = m; mrs[t][1] = rsqrtf(s1*(1.f/S_TOT) - m*m + EPS);
  }
  __syncthreads();
  const float* pin = c2 + n*32*S_TOT + s;
  float acc = bias[c];
  #pragma unroll 8
  for (int i = 0; i < 32; i++) {
    float v = pin[i*S_TOT];
    v = leakyf((v - mrs[i][0]) * mrs[i][1]);
    acc += v * ws[i];
  }
  c3[(n*32 + c)*S_TOT + s] = acc;
  float sm = acc, sq = acc*acc;
  #pragma unroll
  for (int o = 32; o > 0; o >>= 1) { sm += __shfl_down(sm, o); sq += __shfl_down(sq, o); }
  int lane = t & 63, wv = t >> 6;
  if (lane == 0) { red[0][wv] = sm; red[1][wv] = sq; }
  __syncthreads();
  if (t == 0) {
    float a = red[0][0]+red[0][1]+red[0][2]+red[0][3];
    float b = red[1][0]+red[1][1]+red[1][2]+red[1][3];
    atomicAdd(&st3[(n*32+c)*2], a); atomicAdd(&st3[(n*32+c)*2+1], b);
  }
}

// ---------------- IN(c3)+leaky + LayerNorm -> token-major tln[token*32+c] ----------------
__global__ __launch_bounds__(TPB) void k_ln(
    const float* __restrict__ c3, const float* __restrict__ st3,
    const float* __restrict__ lnw, const float* __restrict__ lnb,
    float* __restrict__ tln) {
  __shared__ float mrs[32][2];
  __shared__ float wsh[32], bsh[32];
  int bid = blockIdx.x, t = threadIdx.x;
  int n = bid >> 6; int s = ((bid & 63) << 8) + t;
  if (t < 32) {
    float s0 = st3[(n*32+t)*2], s1 = st3[(n*32+t)*2+1];
    float m = s0 * (1.f/S_TOT);
    mrs[t][0] = m; mrs[t][1] = rsqrtf(s1*(1.f/S_TOT) - m*m + EPS);
    wsh[t] = lnw[t]; bsh[t] = lnb[t];
  }
  __syncthreads();
  float xv[32]; float mean = 0.f;
  #pragma unroll
  for (int c = 0; c < 32; c++) {
    float v = c3[(n*32 + c)*S_TOT + s];
    v = leakyf((v - mrs[c][0]) * mrs[c][1]);
    xv[c] = v; mean += v;
  }
  mean *= (1.f/32.f);
  float var = 0.f;
  #pragma unroll
  for (int c = 0; c < 32; c++) { float d = xv[c] - mean; var += d*d; }
  float rstd = rsqrtf(var*(1.f/32.f) + EPS);
  int token = n*S_TOT + s;
  #pragma unroll
  for (int c = 0; c < 32; c++)
    tln[token*32 + c] = (xv[c] - mean)*rstd*wsh[c] + bsh[c];
}

// ---------------- in_proj ----------------
#define IPT 16
__global__ __launch_bounds__(TPB) void k_inproj(
    const float* __restrict__ tln, const float* __restrict__ ipw,
    float* __restrict__ xi, float* __restrict__ zb) {
  __shared__ float wT[4096];
  __shared__ float tk[IPT][32];
  int t = threadIdx.x; int token0 = blockIdx.x * IPT;
  for (int i = t; i < 4096; i += TPB) { int f = i >> 5, c = i & 31; wT[c*128 + f] = ipw[i]; }
  for (int i = t; i < IPT*32; i += TPB) { int lt = i >> 5, c = i & 31; tk[lt][c] = tln[(token0+lt)*32 + c]; }
  __syncthreads();
  int f = t & 127;
  for (int lt = t >> 7; lt < IPT; lt += 2) {
    float acc = 0.f;
    #pragma unroll
    for (int c = 0; c < 32; c++) acc += wT[c*128 + f] * tk[lt][c];
    int token = token0 + lt;
    if (f < 64) xi[token*64 + f] = acc;
    else        zb[token*64 + (f - 64)] = acc;
  }
}

// ---------------- causal depthwise conv1d + SiLU + x_proj + dt ----------------
__global__ __launch_bounds__(TPB) void k_conv1d(
    const float* __restrict__ xi, const float* __restrict__ c1w,
    const float* __restrict__ c1b, const float* __restrict__ xpw,
    const float* __restrict__ dtw, const float* __restrict__ dtbi,
    float* __restrict__ u, float* __restrict__ dt,
    float* __restrict__ Bb, float* __restrict__ Cc) {
  __shared__ float xpT[2176];
  __shared__ float uu[4][64];
  __shared__ float xd[4][34];
  int t = threadIdx.x;
  for (int i = t; i < 2176; i += TPB) { int f = i >> 6, dd = i & 63; xpT[dd*34 + f] = xpw[i]; }
  __syncthreads();
  int lt = t >> 6, ch = t & 63;
  for (int it = 0; it < 4; it++) {
    int token = blockIdx.x*16 + it*4 + lt;
    int n = token >> 14, s = token & 16383;
    float acc = c1b[ch];
    #pragma unroll
    for (int j = 0; j < 4; j++) {
      int sp = s - 3 + j;
      float v = (sp >= 0) ? xi[((n << 14) + sp)*64 + ch] : 0.f;
      acc += v * c1w[ch*4 + j];
    }
    float uv = acc / (1.f + __expf(-acc));
    u[token*64 + ch] = uv;
    uu[lt][ch] = uv;
    __syncthreads();
    if (ch < 34) {
      float a = 0.f;
      #pragma unroll
      for (int dd = 0; dd < 64; dd++) a += xpT[dd*34 + ch] * uu[lt][dd];
      xd[lt][ch] = a;
    }
    __syncthreads();
    float dv = xd[lt][0]*dtw[ch*2] + xd[lt][1]*dtw[ch*2+1] + dtbi[ch];
    dt[token*64 + ch] = fmaxf(dv, 0.f) + log1pf(__expf(-fabsf(dv)));
    if (ch < 16)       Bb[token*16 + ch]        = xd[lt][2 + ch];
    else if (ch < 32)  Cc[token*16 + (ch - 16)] = xd[lt][2 + ch];
    __syncthreads();
  }
}

// aggregate layout: SIDX(b,d,nn,chunk) = (((b*64+d)*16+nn)*NCHUNK + chunk)  (chunk fastest)

// ---------------- scan phase 1: 4 states/lane, block=(b,chunk) ----------------
__global__ __launch_bounds__(TPB) void k_scan1(
    const float* __restrict__ dt, const float* __restrict__ u,
    const float* __restrict__ Bb, const float* __restrict__ Alog,
    float* __restrict__ cA, float* __restrict__ cX) {
  int bid = blockIdx.x, t = threadIdx.x;
  int chunk = bid & 255, b = bid >> 8;
  int q = t & 3, d = t >> 2;
  float Ar[4];
  #pragma unroll
  for (int j = 0; j < 4; j++) Ar[j] = -__expf(Alog[d*16 + 4*q + j]);
  float h[4] = {0.f, 0.f, 0.f, 0.f};
  float sdt = 0.f;
  int tg0 = b*S_TOT + chunk*CLEN;
  #pragma unroll 4
  for (int tt = 0; tt < CLEN; tt++) {
    int tg = tg0 + tt;
    float dtv = dt[tg*64 + d], uv = u[tg*64 + d];
    sdt += dtv;
    float du = dtv * uv;
    float4 Bq = *(const float4*)(Bb + tg*16 + q*4);
    h[0] = __expf(Ar[0]*dtv)*h[0] + Bq.x*du;
    h[1] = __expf(Ar[1]*dtv)*h[1] + Bq.y*du;
    h[2] = __expf(Ar[2]*dtv)*h[2] + Bq.z*du;
    h[3] = __expf(Ar[3]*dtv)*h[3] + Bq.w*du;
  }
  #pragma unroll
  for (int j = 0; j < 4; j++) {
    int idx = (((b*64 + d)*16 + 4*q + j)*NCHUNK) + chunk;
    cA[idx] = __expf(Ar[j]*sdt);
    cX[idx] = h[j];
  }
}

// ---------------- scan phase 2: wave-per-(b,d,n) Kogge-Stone over chunks ----------------
__global__ __launch_bounds__(TPB) void k_scan2(
    const float* __restrict__ cA, float* __restrict__ cX) {
  int t = threadIdx.x;
  int w = blockIdx.x*4 + (t >> 6);     // 0..2047
  int lane = t & 63;
  int b = w >> 10, d = (w >> 4) & 63, nn = w & 15;
  int base = ((b*64 + d)*16 + nn)*NCHUNK;
  float4 a = *(const float4*)(cA + base + lane*4);
  float4 x = *(const float4*)(cX + base + lane*4);
  // local inclusive compose (chunk order a.x first)
  float A = a.x*a.y*a.z*a.w;
  float X = ((x.x*a.y + x.y)*a.z + x.z)*a.w + x.w;
  #pragma unroll
  for (int off = 1; off < 64; off <<= 1) {
    float Ap = __shfl_up(A, off);
    float Xp = __shfl_up(X, off);
    if (lane >= off) { X = A*Xp + X; A = A*Ap; }
  }
  float Xe = __shfl_up(X, 1);
  if (lane == 0) Xe = 0.f;
  float r = Xe;
  float4 o;
  o.x = r; r = a.x*r + x.x;
  o.y = r; r = a.y*r + x.y;
  o.z = r; r = a.z*r + x.z;
  o.w = r;
  *(float4*)(cX + base + lane*4) = o;
}

// ---------------- scan phase 3: seeded replay, 4 states/lane, quad butterfly ----------------
__global__ __launch_bounds__(TPB) void k_scan3(
    const float* __restrict__ dt, const float* __restrict__ u,
    const float* __restrict__ Bb, const float* __restrict__ Cc,
    const float* __restrict__ Alog, const float* __restrict__ Dp,
    const float* __restrict__ zb, const float* __restrict__ cX,
    float* __restrict__ g) {
  int bid = blockIdx.x, t = threadIdx.x;
  int chunk = bid & 255, b = bid >> 8;
  int q = t & 3, d = t >> 2;
  float Ar[4];
  #pragma unroll
  for (int j = 0; j < 4; j++) Ar[j] = -__expf(Alog[d*16 + 4*q + j]);
  float h[4];
  #pragma unroll
  for (int j = 0; j < 4; j++)
    h[j] = cX[(((b*64 + d)*16 + 4*q + j)*NCHUNK) + chunk];
  float Dv = Dp[d];
  int tg0 = b*S_TOT + chunk*CLEN;
  #pragma unroll 4
  for (int tt = 0; tt < CLEN; tt++) {
    int tg = tg0 + tt;
    float dtv = dt[tg*64 + d], uv = u[tg*64 + d];
    float du = dtv * uv;
    float4 Bq = *(const float4*)(Bb + tg*16 + q*4);
    float4 Cq = *(const float4*)(Cc + tg*16 + q*4);
    h[0] = __expf(Ar[0]*dtv)*h[0] + Bq.x*du;
    h[1] = __expf(Ar[1]*dtv)*h[1] + Bq.y*du;
    h[2] = __expf(Ar[2]*dtv)*h[2] + Bq.z*du;
    h[3] = __expf(Ar[3]*dtv)*h[3] + Bq.w*du;
    float yp = h[0]*Cq.x + h[1]*Cq.y + h[2]*Cq.z + h[3]*Cq.w;
    yp += __shfl_xor(yp, 1);
    yp += __shfl_xor(yp, 2);
    if (q == 0) {
      float zv = zb[tg*64 + d];
      float y = yp + uv*Dv;
      g[tg*64 + d] = y * (zv / (1.f + __expf(-zv)));
    }
  }
}

// ---------------- out_proj ----------------
__global__ __launch_bounds__(TPB) void k_out(
    const float* __restrict__ g, const float* __restrict__ opw,
    float* __restrict__ out) {
  __shared__ float wrow[64];
  int bid = blockIdx.x, t = threadIdx.x;
  int s = ((bid & 63) << 8) + t, c = (bid >> 6) & 31, n = bid >> 11;
  if (t < 64) wrow[t] = opw[c*64 + t];
  __syncthreads();
  const float4* gp = (const float4*)(g + ((n << 14) + s)*64);
  float acc = 0.f;
  #pragma unroll
  for (int qq = 0; qq < 16; qq++) {
    float4 v = gp[qq];
    acc += v.x*wrow[4*qq] + v.y*wrow[4*qq+1] + v.z*wrow[4*qq+2] + v.w*wrow[4*qq+3];
  }
  out[(n*32 + c)*S_TOT + s] = acc;
}

extern "C" void kernel_launch(void* const* d_in, const int* in_sizes, int n_in,
                              void* d_out, int out_size, void* d_ws, size_t ws_size,
                              hipStream_t stream) {
  const float* x1    = (const float*)d_in[0];
  const float* x2    = (const float*)d_in[1];
  const float* upw   = (const float*)d_in[2];
  const float* upb   = (const float*)d_in[3];
  const float* dc1w  = (const float*)d_in[4];
  const float* dc1b  = (const float*)d_in[5];
  const float* dc2w  = (const float*)d_in[6];
  const float* dc2b  = (const float*)d_in[7];
  const float* dc3w  = (const float*)d_in[8];
  const float* dc3b  = (const float*)d_in[9];
  const float* lnw   = (const float*)d_in[10];
  const float* lnb   = (const float*)d_in[11];
  const float* ipw   = (const float*)d_in[12];
  const float* c1w   = (const float*)d_in[13];
  const float* c1b   = (const float*)d_in[14];
  const float* xpw   = (const float*)d_in[15];
  const float* dtw   = (const float*)d_in[16];
  const float* dtbi  = (const float*)d_in[17];
  const float* Alog  = (const float*)d_in[18];
  const float* Dp    = (const float*)d_in[19];
  const float* opw   = (const float*)d_in[20];
  float* out = (float*)d_out;

  float* ws   = (float*)d_ws;
  float* xcat = ws + 0;            // 2,097,152  (reused: c3 -> xi -> g)
  float* c1   = ws + 2097152;      // 1,048,576  (reused: tln -> Bb|Cc)
  float* c2   = ws + 3145728;      // 1,048,576
  float* zb   = ws + 4194304;      // 2,097,152  (pn aliases this, dead before inproj)
  float* ub   = ws + 6291456;      // 2,097,152
  float* dtb  = ws + 8388608;      // 2,097,152
  float* cA   = ws + 10485760;     // 524,288
  float* cX   = ws + 11010048;     // 524,288
  float* st   = ws + 11534336;     // 384 = st1|st2|st3
  float* st1 = st, *st2 = st + 128, *st3 = st + 256;
  float* c3   = xcat;
  float* tln  = c1;
  float* xi   = xcat;
  float* Bb   = c1;
  float* Cc   = c1 + BATCH*S_TOT*NST;
  float* gbuf = xcat;
  float* pn   = zb;                // 2*32*18*1156 = 1,331,712 floats

  hipMemsetAsync(st, 0, 384*sizeof(float), stream);
  hipMemsetAsync(pn, 0, (size_t)2*32*18*1156*sizeof(float), stream);
  k_upconcat<<<8192, TPB, 0, stream>>>(x1, x2, upw, upb, xcat);
  k_conv1   <<<4096, TPB, 0, stream>>>(xcat, dc1w, dc1b, c1, st1);
  k_pad_norm<<<4096, TPB, 0, stream>>>(c1, st1, pn);
  k_conv2   <<<1024, TPB, 0, stream>>>(pn, dc2w, dc2b, c2, st2);
  k_conv3   <<<4096, TPB, 0, stream>>>(c2, dc3w, dc3b, st2, c3, st3);
  k_ln      <<<128,  TPB, 0, stream>>>(c3, st3, lnw, lnb, tln);
  k_inproj  <<<2048, TPB, 0, stream>>>(tln, ipw, xi, zb);
  k_conv1d  <<<2048, TPB, 0, stream>>>(xi, c1w, c1b, xpw, dtw, dtbi, ub, dtb, Bb, Cc);
  k_scan1   <<<512,  TPB, 0, stream>>>(dtb, ub, Bb, Alog, cA, cX);
  k_scan2   <<<512,  TPB, 0, stream>>>(cA, cX);
  k_scan3   <<<512,  TPB, 0, stream>>>(dtb, ub, Bb, Cc, Alog, Dp, zb, cX, gbuf);
  k_out     <<<4096, TPB, 0, stream>>>(gbuf, opw, out);
}

// Round 4
// 247.014 us; speedup vs baseline: 1.9628x; 1.5505x over previous
//
#include <hip/hip_runtime.h>

#define TPB 256
#define BATCH 2
#define S_TOT 16384        // 16*32*32 spatial positions
#define NST 16
#define NCHUNK 256
#define CLEN 64
#define EPS 1e-5f
#define SLOPE 0.01f

__device__ __forceinline__ float leakyf(float v){ return v > 0.f ? v : SLOPE * v; }
__device__ __forceinline__ float siluf(float v){ return v / (1.f + __expf(-v)); }

// ---------------- up half of ConvTranspose3d(k=2,s=2): up[n][o][s], 8 o per thread ----------------
__global__ __launch_bounds__(TPB) void k_up(
    const float* __restrict__ x1, const float* __restrict__ upw,
    const float* __restrict__ upb, float* __restrict__ up) {
  __shared__ float wq[2048];              // [c(32)][o'(8)][tap(8)]
  int t = threadIdx.x;
  int idx = blockIdx.x * TPB + t;         // 131072 = 4 qsplit * 2 n * 16384 s
  int s = idx & 16383;
  int n = (idx >> 14) & 1;
  int q = idx >> 15;                      // block-uniform
  for (int i = t; i < 2048; i += TPB) {
    int c = i >> 6;
    wq[i] = upw[c*256 + q*64 + (i & 63)];
  }
  __syncthreads();
  int z = s >> 10, y = (s >> 5) & 31, x = s & 31;
  int tap = ((z & 1)*2 + (y & 1))*2 + (x & 1);
  int xb = n*65536 + (z >> 1)*256 + (y >> 1)*16 + (x >> 1);
  float xv[32];
  #pragma unroll
  for (int c = 0; c < 32; c++) xv[c] = x1[xb + c*2048];
  float acc[8];
  #pragma unroll
  for (int j = 0; j < 8; j++) acc[j] = upb[q*8 + j];
  #pragma unroll
  for (int c = 0; c < 32; c++) {
    #pragma unroll
    for (int j = 0; j < 8; j++)
      acc[j] += xv[c] * wq[c*64 + j*8 + tap];
  }
  #pragma unroll
  for (int j = 0; j < 8; j++)
    up[(n*32 + q*8 + j)*S_TOT + s] = acc[j];
}

// ---------------- dc1: 1x1x1 conv 64->32 (inputs x2|up), 8 oc per thread, + stats ----------------
__global__ __launch_bounds__(TPB) void k_conv1(
    const float* __restrict__ x2, const float* __restrict__ up,
    const float* __restrict__ w, const float* __restrict__ bias,
    float* __restrict__ c1, float* __restrict__ st1) {
  __shared__ float ws[512];               // [j(8)][i(64)]
  __shared__ float red[4][8][2];
  int t = threadIdx.x;
  int idx = blockIdx.x * TPB + t;
  int s = idx & 16383;
  int n = (idx >> 14) & 1;
  int q = idx >> 15;
  int c0 = q*8;
  for (int i = t; i < 512; i += TPB) ws[i] = w[c0*64 + i];
  __syncthreads();
  const float* px2 = x2 + n*32*S_TOT + s;
  const float* pup = up + n*32*S_TOT + s;
  float acc[8];
  #pragma unroll
  for (int j = 0; j < 8; j++) acc[j] = bias[c0 + j];
  #pragma unroll
  for (int i = 0; i < 32; i++) {
    float v = px2[i*S_TOT];
    #pragma unroll
    for (int j = 0; j < 8; j++) acc[j] += v * ws[j*64 + i];
  }
  #pragma unroll
  for (int i = 0; i < 32; i++) {
    float v = pup[i*S_TOT];
    #pragma unroll
    for (int j = 0; j < 8; j++) acc[j] += v * ws[j*64 + 32 + i];
  }
  #pragma unroll
  for (int j = 0; j < 8; j++)
    c1[(n*32 + c0 + j)*S_TOT + s] = acc[j];
  int wv = t >> 6;
  #pragma unroll
  for (int j = 0; j < 8; j++) {
    float sm = acc[j], sq = acc[j]*acc[j];
    #pragma unroll
    for (int o = 32; o > 0; o >>= 1) { sm += __shfl_down(sm, o); sq += __shfl_down(sq, o); }
    if ((t & 63) == 0) { red[wv][j][0] = sm; red[wv][j][1] = sq; }
  }
  __syncthreads();
  if (t < 16) {
    int j = t >> 1, m = t & 1;
    float a = red[0][j][m] + red[1][j][m] + red[2][j][m] + red[3][j][m];
    atomicAdd(&st1[(n*32 + c0 + j)*2 + m], a);
  }
}

// ---------------- IN(c1)+leaky into padded pn[slice][18][34][34], halo zeroed here ----------------
__global__ __launch_bounds__(TPB) void k_pad(
    const float* __restrict__ c1, const float* __restrict__ st1,
    float* __restrict__ pn) {
  int slice = blockIdx.y;                 // n*32+c
  int i = blockIdx.x * TPB + threadIdx.x; // < 20808 = 18*34*34
  if (i >= 20808) return;
  float s0 = st1[slice*2], s1 = st1[slice*2 + 1];
  float m = s0 * (1.f/S_TOT);
  float rs = rsqrtf(s1*(1.f/S_TOT) - m*m + EPS);
  int zp = i / 1156; int r = i - zp*1156; int yp = r / 34; int xp = r - yp*34;
  float v = 0.f;
  if (zp >= 1 && zp <= 16 && yp >= 1 && yp <= 32 && xp >= 1 && xp <= 32)
    v = leakyf((c1[slice*S_TOT + (zp-1)*1024 + (yp-1)*32 + (xp-1)] - m) * rs);
  pn[slice*20808 + i] = v;
}

// ---------------- dc2: 3x3x3 grouped conv, 4 outputs/thread (unchanged, verified) ----------------
__global__ __launch_bounds__(TPB) void k_conv2(
    const float* __restrict__ pn, const float* __restrict__ w,
    const float* __restrict__ bias, float* __restrict__ c2,
    float* __restrict__ st2) {
  __shared__ float ws[432];
  __shared__ float red[4][4][2];
  int bid = blockIdx.x, t = threadIdx.x;
  int s = ((bid & 63) << 8) + t;
  int g = (bid >> 6) & 7;
  int n = bid >> 9;
  for (int i = t; i < 432; i += TPB) ws[i] = w[(g*4)*108 + i];
  __syncthreads();
  int z = s >> 10, y = (s >> 5) & 31, x = s & 31;
  float acc[4];
  #pragma unroll
  for (int oc = 0; oc < 4; oc++) acc[oc] = bias[g*4 + oc];
  const float* pbase = pn + ((n*32 + g*4)*18)*1156;
  #pragma unroll
  for (int ic = 0; ic < 4; ic++) {
    const float* pc = pbase + ic*(18*1156);
    #pragma unroll
    for (int dz = 0; dz < 3; dz++) {
      #pragma unroll
      for (int dy = 0; dy < 3; dy++) {
        const float* pr = pc + (z+dz)*1156 + (y+dy)*34 + x;
        float p0 = pr[0], p1 = pr[1], p2 = pr[2];
        int wb = ic*27 + dz*9 + dy*3;
        #pragma unroll
        for (int oc = 0; oc < 4; oc++) {
          const float* wo = &ws[oc*108 + wb];
          acc[oc] += p0*wo[0] + p1*wo[1] + p2*wo[2];
        }
      }
    }
  }
  float sm[4], sq[4];
  #pragma unroll
  for (int oc = 0; oc < 4; oc++) {
    c2[(n*32 + g*4 + oc)*S_TOT + s] = acc[oc];
    sm[oc] = acc[oc]; sq[oc] = acc[oc]*acc[oc];
  }
  #pragma unroll
  for (int o = 32; o > 0; o >>= 1) {
    #pragma unroll
    for (int oc = 0; oc < 4; oc++) {
      sm[oc] += __shfl_down(sm[oc], o);
      sq[oc] += __shfl_down(sq[oc], o);
    }
  }
  int lane = t & 63, wv = t >> 6;
  if (lane == 0) {
    #pragma unroll
    for (int oc = 0; oc < 4; oc++) { red[wv][oc][0] = sm[oc]; red[wv][oc][1] = sq[oc]; }
  }
  __syncthreads();
  if (t < 8) {
    int oc = t & 3, m = t >> 2;
    float a = red[0][oc][m] + red[1][oc][m] + red[2][oc][m] + red[3][oc][m];
    atomicAdd(&st2[(n*32 + g*4 + oc)*2 + m], a);
  }
}

// ---------------- dc3: 1x1x1 conv 32->32, IN(c2)+leaky on read, 8 oc per thread ----------------
__global__ __launch_bounds__(TPB) void k_conv3(
    const float* __restrict__ c2, const float* __restrict__ w,
    const float* __restrict__ bias, const float* __restrict__ st2,
    float* __restrict__ c3, float* __restrict__ st3) {
  __shared__ float ws[256];               // [j(8)][i(32)]
  __shared__ float mrs[32][2];
  __shared__ float red[4][8][2];
  int t = threadIdx.x;
  int idx = blockIdx.x * TPB + t;
  int s = idx & 16383;
  int n = (idx >> 14) & 1;
  int q = idx >> 15;
  int c0 = q*8;
  if (t < 256) ws[t] = w[c0*32 + t];
  if (t < 32) {
    float s0 = st2[(n*32+t)*2], s1 = st2[(n*32+t)*2+1];
    float m = s0 * (1.f/S_TOT);
    mrs[t][0] = m; mrs[t][1] = rsqrtf(s1*(1.f/S_TOT) - m*m + EPS);
  }
  __syncthreads();
  const float* pin = c2 + n*32*S_TOT + s;
  float acc[8];
  #pragma unroll
  for (int j = 0; j < 8; j++) acc[j] = bias[c0 + j];
  #pragma unroll
  for (int i = 0; i < 32; i++) {
    float v = leakyf((pin[i*S_TOT] - mrs[i][0]) * mrs[i][1]);
    #pragma unroll
    for (int j = 0; j < 8; j++) acc[j] += v * ws[j*32 + i];
  }
  #pragma unroll
  for (int j = 0; j < 8; j++)
    c3[(n*32 + c0 + j)*S_TOT + s] = acc[j];
  int wv = t >> 6;
  #pragma unroll
  for (int j = 0; j < 8; j++) {
    float sm = acc[j], sq = acc[j]*acc[j];
    #pragma unroll
    for (int o = 32; o > 0; o >>= 1) { sm += __shfl_down(sm, o); sq += __shfl_down(sq, o); }
    if ((t & 63) == 0) { red[wv][j][0] = sm; red[wv][j][1] = sq; }
  }
  __syncthreads();
  if (t < 16) {
    int j = t >> 1, m = t & 1;
    float a = red[0][j][m] + red[1][j][m] + red[2][j][m] + red[3][j][m];
    atomicAdd(&st3[(n*32 + c0 + j)*2 + m], a);
  }
}

// ---------------- in_proj fused with IN(c3)+leaky + LayerNorm ----------------
// acc_f = rstd*(dot(W2[f],x) - mean*S1[f]) + S2[f],  W2 = ipw*lnw, S2 = ipw·lnb
__global__ __launch_bounds__(TPB) void k_inproj(
    const float* __restrict__ c3, const float* __restrict__ st3,
    const float* __restrict__ lnw, const float* __restrict__ lnb,
    const float* __restrict__ ipw,
    float* __restrict__ xi, float* __restrict__ zb) {
  __shared__ float W2T[4096];             // [c(32)][f(128)]
  __shared__ float tk[16*33];             // [lt][c] padded
  __shared__ float S1[128], S2[128];
  __shared__ float mv[16][2];
  __shared__ float mrs[32][2];
  int t = threadIdx.x;
  int token0 = blockIdx.x * 16;
  int n = token0 >> 14;
  int s0 = token0 & 16383;
  if (t < 32) {
    float a = st3[(n*32+t)*2], b = st3[(n*32+t)*2+1];
    float m = a * (1.f/S_TOT);
    mrs[t][0] = m; mrs[t][1] = rsqrtf(b*(1.f/S_TOT) - m*m + EPS);
  }
  __syncthreads();
  for (int i = t; i < 4096; i += TPB) {
    int f = i >> 5, c = i & 31;
    W2T[c*128 + f] = ipw[i] * lnw[c];
  }
  for (int i = t; i < 512; i += TPB) {
    int c = i >> 4, lt = i & 15;
    float raw = c3[(n*32 + c)*S_TOT + s0 + lt];
    tk[lt*33 + c] = leakyf((raw - mrs[c][0]) * mrs[c][1]);
  }
  __syncthreads();
  if (t < 128) {
    float a = 0.f, b = 0.f;
    #pragma unroll
    for (int c = 0; c < 32; c++) { a += W2T[c*128 + t]; b += ipw[t*32 + c]*lnb[c]; }
    S1[t] = a; S2[t] = b;
  }
  if (t < 16) {
    float mean = 0.f;
    #pragma unroll
    for (int c = 0; c < 32; c++) mean += tk[t*33 + c];
    mean *= (1.f/32.f);
    float var = 0.f;
    #pragma unroll
    for (int c = 0; c < 32; c++) { float d = tk[t*33 + c] - mean; var += d*d; }
    mv[t][0] = mean; mv[t][1] = rsqrtf(var*(1.f/32.f) + EPS);
  }
  __syncthreads();
  int f = t & 127, half = t >> 7;
  for (int lt = half; lt < 16; lt += 2) {
    float acc = 0.f;
    #pragma unroll
    for (int c = 0; c < 32; c++) acc += W2T[c*128 + f] * tk[lt*33 + c];
    float r = mv[lt][1]*(acc - mv[lt][0]*S1[f]) + S2[f];
    int token = token0 + lt;
    if (f < 64) xi[token*64 + f] = r;
    else        zb[token*64 + (f - 64)] = r;
  }
}

// ---------------- causal depthwise conv1d + SiLU + x_proj + dt (2 syncs) ----------------
__global__ __launch_bounds__(TPB) void k_conv1d(
    const float* __restrict__ xi, const float* __restrict__ c1w,
    const float* __restrict__ c1b, const float* __restrict__ xpw,
    const float* __restrict__ dtw, const float* __restrict__ dtbi,
    float* __restrict__ u, float* __restrict__ dt,
    float* __restrict__ Bb, float* __restrict__ Cc) {
  __shared__ float xpT[2176];             // [dd(64)][f(34)]
  __shared__ float uu[16*64];
  __shared__ float xd[16*34];
  int t = threadIdx.x;
  int token0 = blockIdx.x * 16;
  for (int i = t; i < 2176; i += TPB) { int f = i >> 6, dd = i & 63; xpT[dd*34 + f] = xpw[i]; }
  int ch = t & 63;
  float cw0 = c1w[ch*4], cw1 = c1w[ch*4+1], cw2 = c1w[ch*4+2], cw3 = c1w[ch*4+3];
  float cb = c1b[ch];
  #pragma unroll
  for (int r = 0; r < 4; r++) {
    int lt = (t >> 6) + 4*r;
    int token = token0 + lt;
    int n = token >> 14, s = token & 16383;
    int base = (n << 14)*64;
    float acc = cb;
    float v0 = (s >= 3) ? xi[base + (s-3)*64 + ch] : 0.f;
    float v1 = (s >= 2) ? xi[base + (s-2)*64 + ch] : 0.f;
    float v2 = (s >= 1) ? xi[base + (s-1)*64 + ch] : 0.f;
    float v3 = xi[base + s*64 + ch];
    acc += v0*cw0 + v1*cw1 + v2*cw2 + v3*cw3;
    float uv = siluf(acc);
    u[token*64 + ch] = uv;
    uu[lt*64 + ch] = uv;
  }
  __syncthreads();
  for (int i = t; i < 544; i += TPB) {
    int lt = i / 34; int f = i - lt*34;
    float a = 0.f;
    #pragma unroll
    for (int dd = 0; dd < 64; dd++) a += xpT[dd*34 + f] * uu[lt*64 + dd];
    xd[lt*34 + f] = a;
  }
  __syncthreads();
  float dw0 = dtw[ch*2], dw1 = dtw[ch*2+1], dbv = dtbi[ch];
  #pragma unroll
  for (int r = 0; r < 4; r++) {
    int lt = (t >> 6) + 4*r;
    int token = token0 + lt;
    float dv = xd[lt*34]*dw0 + xd[lt*34+1]*dw1 + dbv;
    dt[token*64 + ch] = fmaxf(dv, 0.f) + log1pf(__expf(-fabsf(dv)));
    if (ch < 16)      Bb[token*16 + ch]      = xd[lt*34 + 2 + ch];
    else if (ch < 32) Cc[token*16 + ch - 16] = xd[lt*34 + 2 + ch];
  }
}

// aggregate layout: (((b*64+d)*16+nn)*NCHUNK + chunk)

// ---------------- scan phase 1: LDS-staged tiles, 4 states/lane ----------------
__global__ __launch_bounds__(TPB) void k_scan1(
    const float* __restrict__ dt, const float* __restrict__ u,
    const float* __restrict__ Bb, const float* __restrict__ Alog,
    float* __restrict__ cA, float* __restrict__ cX) {
  __shared__ __align__(16) float sdt[1024], su[1024], sB[256];
  int bid = blockIdx.x, t = threadIdx.x;
  int chunk = bid & 255, b = bid >> 8;
  int q = t & 3, d = t >> 2;
  float Ar[4];
  #pragma unroll
  for (int j = 0; j < 4; j++) Ar[j] = -__expf(Alog[d*16 + 4*q + j]);
  float h[4] = {0.f,0.f,0.f,0.f};
  float sdts = 0.f;
  int tg0 = b*S_TOT + chunk*CLEN;
  for (int tile = 0; tile < 4; tile++) {
    int base = tg0 + tile*16;
    for (int i = t; i < 1024; i += TPB) { sdt[i] = dt[base*64 + i]; su[i] = u[base*64 + i]; }
    sB[t] = Bb[base*16 + t];
    __syncthreads();
    #pragma unroll
    for (int tt = 0; tt < 16; tt++) {
      float dtv = sdt[tt*64 + d], uv = su[tt*64 + d];
      sdts += dtv;
      float du = dtv * uv;
      float4 Bq = *(const float4*)(sB + tt*16 + q*4);
      h[0] = __expf(Ar[0]*dtv)*h[0] + Bq.x*du;
      h[1] = __expf(Ar[1]*dtv)*h[1] + Bq.y*du;
      h[2] = __expf(Ar[2]*dtv)*h[2] + Bq.z*du;
      h[3] = __expf(Ar[3]*dtv)*h[3] + Bq.w*du;
    }
    __syncthreads();
  }
  #pragma unroll
  for (int j = 0; j < 4; j++) {
    int idx = (((b*64 + d)*16 + 4*q + j)*NCHUNK) + chunk;
    cA[idx] = __expf(Ar[j]*sdts);
    cX[idx] = h[j];
  }
}

// ---------------- scan phase 2: wave-per-(b,d,n) Kogge-Stone over chunks ----------------
__global__ __launch_bounds__(TPB) void k_scan2(
    const float* __restrict__ cA, float* __restrict__ cX) {
  int t = threadIdx.x;
  int w = blockIdx.x*4 + (t >> 6);
  int lane = t & 63;
  int b = w >> 10, d = (w >> 4) & 63, nn = w & 15;
  int base = ((b*64 + d)*16 + nn)*NCHUNK;
  float4 a = *(const float4*)(cA + base + lane*4);
  float4 x = *(const float4*)(cX + base + lane*4);
  float A = a.x*a.y*a.z*a.w;
  float X = ((x.x*a.y + x.y)*a.z + x.z)*a.w + x.w;
  #pragma unroll
  for (int off = 1; off < 64; off <<= 1) {
    float Ap = __shfl_up(A, off);
    float Xp = __shfl_up(X, off);
    if (lane >= off) { X = A*Xp + X; A = A*Ap; }
  }
  float Xe = __shfl_up(X, 1);
  if (lane == 0) Xe = 0.f;
  float r = Xe;
  float4 o;
  o.x = r; r = a.x*r + x.x;
  o.y = r; r = a.y*r + x.y;
  o.z = r; r = a.z*r + x.z;
  o.w = r;
  *(float4*)(cX + base + lane*4) = o;
}

// ---------------- scan phase 3: seeded replay, g written d-major ----------------
__global__ __launch_bounds__(TPB) void k_scan3(
    const float* __restrict__ dt, const float* __restrict__ u,
    const float* __restrict__ Bb, const float* __restrict__ Cc,
    const float* __restrict__ Alog, const float* __restrict__ Dp,
    const float* __restrict__ zb, const float* __restrict__ cX,
    float* __restrict__ g) {
  __shared__ __align__(16) float sdt[1024], su[1024], sz[1024], sB[256], sC[256];
  int bid = blockIdx.x, t = threadIdx.x;
  int chunk = bid & 255, b = bid >> 8;
  int q = t & 3, d = t >> 2;
  float Ar[4];
  #pragma unroll
  for (int j = 0; j < 4; j++) Ar[j] = -__expf(Alog[d*16 + 4*q + j]);
  float h[4];
  #pragma unroll
  for (int j = 0; j < 4; j++)
    h[j] = cX[(((b*64 + d)*16 + 4*q + j)*NCHUNK) + chunk];
  float Dv = Dp[d];
  int tg0 = b*S_TOT + chunk*CLEN;
  float* grow = g + (b*64 + d)*S_TOT + chunk*CLEN;
  for (int tile = 0; tile < 4; tile++) {
    int base = tg0 + tile*16;
    for (int i = t; i < 1024; i += TPB) {
      sdt[i] = dt[base*64 + i]; su[i] = u[base*64 + i]; sz[i] = zb[base*64 + i];
    }
    sB[t] = Bb[base*16 + t];
    sC[t] = Cc[base*16 + t];
    __syncthreads();
    #pragma unroll
    for (int tt = 0; tt < 16; tt++) {
      float dtv = sdt[tt*64 + d], uv = su[tt*64 + d];
      float du = dtv * uv;
      float4 Bq = *(const float4*)(sB + tt*16 + q*4);
      float4 Cq = *(const float4*)(sC + tt*16 + q*4);
      h[0] = __expf(Ar[0]*dtv)*h[0] + Bq.x*du;
      h[1] = __expf(Ar[1]*dtv)*h[1] + Bq.y*du;
      h[2] = __expf(Ar[2]*dtv)*h[2] + Bq.z*du;
      h[3] = __expf(Ar[3]*dtv)*h[3] + Bq.w*du;
      float yp = h[0]*Cq.x + h[1]*Cq.y + h[2]*Cq.z + h[3]*Cq.w;
      yp += __shfl_xor(yp, 1);
      yp += __shfl_xor(yp, 2);
      if (q == 0) {
        float zv = sz[tt*64 + d];
        grow[tile*16 + tt] = (yp + uv*Dv) * siluf(zv);
      }
    }
    __syncthreads();
  }
}

// ---------------- out_proj: out[c][s] = sum_d g[d][s]*opw[c][d], 8 oc per thread ----------------
__global__ __launch_bounds__(TPB) void k_out(
    const float* __restrict__ g, const float* __restrict__ opw,
    float* __restrict__ out) {
  __shared__ float ws[512];               // [j(8)][dd(64)]
  int t = threadIdx.x;
  int idx = blockIdx.x * TPB + t;
  int s = idx & 16383;
  int n = (idx >> 14) & 1;
  int q = idx >> 15;
  int c0 = q*8;
  for (int i = t; i < 512; i += TPB) ws[i] = opw[c0*64 + i];
  __syncthreads();
  const float* pg = g + n*64*S_TOT + s;
  float acc[8] = {0.f,0.f,0.f,0.f,0.f,0.f,0.f,0.f};
  #pragma unroll
  for (int dd = 0; dd < 64; dd++) {
    float v = pg[dd*S_TOT];
    #pragma unroll
    for (int j = 0; j < 8; j++) acc[j] += v * ws[j*64 + dd];
  }
  #pragma unroll
  for (int j = 0; j < 8; j++)
    out[(n*32 + c0 + j)*S_TOT + s] = acc[j];
}

extern "C" void kernel_launch(void* const* d_in, const int* in_sizes, int n_in,
                              void* d_out, int out_size, void* d_ws, size_t ws_size,
                              hipStream_t stream) {
  const float* x1    = (const float*)d_in[0];
  const float* x2    = (const float*)d_in[1];
  const float* upw   = (const float*)d_in[2];
  const float* upb   = (const float*)d_in[3];
  const float* dc1w  = (const float*)d_in[4];
  const float* dc1b  = (const float*)d_in[5];
  const float* dc2w  = (const float*)d_in[6];
  const float* dc2b  = (const float*)d_in[7];
  const float* dc3w  = (const float*)d_in[8];
  const float* dc3b  = (const float*)d_in[9];
  const float* lnw   = (const float*)d_in[10];
  const float* lnb   = (const float*)d_in[11];
  const float* ipw   = (const float*)d_in[12];
  const float* c1w   = (const float*)d_in[13];
  const float* c1b   = (const float*)d_in[14];
  const float* xpw   = (const float*)d_in[15];
  const float* dtw   = (const float*)d_in[16];
  const float* dtbi  = (const float*)d_in[17];
  const float* Alog  = (const float*)d_in[18];
  const float* Dp    = (const float*)d_in[19];
  const float* opw   = (const float*)d_in[20];
  float* out = (float*)d_out;

  float* ws = (float*)d_ws;
  // lifetimes: ubuf[0,1M) -> c3[0,1M) -> cA/cX[0,1M)
  //            c1[1M,2M) ; pn[2M,3.43M) -> xi[1M,3M) -> g[1M,3M)
  //            c2[3.43M,4.48M) -> Bb/Cc same region
  float* ubuf = ws + 0;            // 1,048,576
  float* c1   = ws + 1048576;      // 1,048,576
  float* pn   = ws + 2097152;      // 1,331,712 (2*32*18*34*34)
  float* c2   = ws + 3428864;      // 1,048,576
  float* c3   = ws + 0;            // reuse ubuf (dead after conv1)
  float* xi   = ws + 1048576;      // 2,097,152 reuse c1+pn (dead after conv2)
  float* zb   = ws + 4477440;      // 2,097,152
  float* ub   = ws + 6574592;      // 2,097,152
  float* dtb  = ws + 8671744;      // 2,097,152
  float* Bb   = ws + 3428864;      // 524,288 reuse c2 (dead after conv3)
  float* Cc   = ws + 3953152;      // 524,288
  float* cA   = ws + 0;            // 524,288 reuse c3 (dead after inproj)
  float* cX   = ws + 524288;       // 524,288
  float* gbuf = ws + 1048576;      // 2,097,152 reuse xi (dead after conv1d)
  float* st   = ws + 10768896;     // 384
  float* st1 = st, *st2 = st + 128, *st3 = st + 256;

  hipMemsetAsync(st, 0, 384*sizeof(float), stream);
  k_up     <<<512,  TPB, 0, stream>>>(x1, upw, upb, ubuf);
  k_conv1  <<<512,  TPB, 0, stream>>>(x2, ubuf, dc1w, dc1b, c1, st1);
  k_pad    <<<dim3(82,64), TPB, 0, stream>>>(c1, st1, pn);
  k_conv2  <<<1024, TPB, 0, stream>>>(pn, dc2w, dc2b, c2, st2);
  k_conv3  <<<512,  TPB, 0, stream>>>(c2, dc3w, dc3b, st2, c3, st3);
  k_inproj <<<2048, TPB, 0, stream>>>(c3, st3, lnw, lnb, ipw, xi, zb);
  k_conv1d <<<2048, TPB, 0, stream>>>(xi, c1w, c1b, xpw, dtw, dtbi, ub, dtb, Bb, Cc);
  k_scan1  <<<512,  TPB, 0, stream>>>(dtb, ub, Bb, Alog, cA, cX);
  k_scan2  <<<512,  TPB, 0, stream>>>(cA, cX);
  k_scan3  <<<512,  TPB, 0, stream>>>(dtb, ub, Bb, Cc, Alog, Dp, zb, cX, gbuf);
  k_out    <<<512,  TPB, 0, stream>>>(gbuf, opw, out);
}